// Round 5
// baseline (1615.366 us; speedup 1.0000x reference)
//
#include <hip/hip_runtime.h>

// RWKV block on MI355X (gfx950).  B=8, T=2048, C=1024, M=16384.
// R8: halved LDS read traffic in the 8-phase GEMM.  R7 showed the vmcnt
//     lag was NOT the stall (R6->R7 identical); arithmetic says the old
//     scattered 64x32-quadrant wave mapping re-read A/B halves every
//     phase (12 ds_read_b128/lane/phase = 98KB/CU/phase ~ 1150cy at
//     85B/cy, serialized with ~620cy MFMA by lgkm(0)+barrier).  New
//     mapping (m201-style): wave (wm=wave>>2, wn=wave&3) owns contiguous
//     rows wm*128+[0,128), cols wn*64+[0,64); per K-tile each fragment is
//     read ONCE into registers (24 reads/lane/K-tile vs 48) and held:
//       ph0: read av0(8)+bv0(4), lgkm(0), MFMA (a0,s0)
//       ph1: read av1(8)+bv1(4), lgkm(4), MFMA (a1,s0)   [bv1 in flight]
//       ph2: lgkm(0), MFMA (a0,s1)        ph3: MFMA (a1,s1)
//     Since all waves read all 4 halves of a buffer at ph0/ph1, staging:
//       p0:b1.B0  p1:b1.A1  p2:b1.B1 (<-t+1), p3:b0.A0 p4:b0.B0 p5:b0.A1
//       p6:b0.B1 (<-t+2), p7:b1.A0 (<-t+3)
//     Overwrite audit: b0 reads issued p0/p1, drained by p2's lgkm(0)
//     -> b0 restage at p3+ OK.  b1 reads p4/p5, drained p6 -> restage p7+ OK.
//     Landing audit: end-p3 vmcnt(2) covers b1 = {p7-prev,p0,p1,p2} for
//     p4 reads; end-p7 vmcnt(2) covers b0 = {p3,p4,p5,p6} for next p0.
//     Prologue: b0 all + b1.A0 (5 stages), vmcnt(2).
// R5-R7: 256^2 8-phase schedule, BK=64, 8 waves, 128 KiB LDS dbuf, raw
//     s_barrier, setprio around MFMA, XOR-chunk swizzle.  WKV: R3 scan.

#define Bb 8
#define T 2048
#define C 1024
#define M (Bb*T)
#define LCH 32            // chunk length
#define NCH 64            // chunks per sequence (T/LCH)
#define NCI (Bb*NCH)      // 512 chunk instances
#define WKV_THREADS (NCI*C)   // 524288

typedef unsigned short u16;
typedef unsigned int u32;
typedef __bf16 bf16x8 __attribute__((ext_vector_type(8)));
typedef float f32x4 __attribute__((ext_vector_type(4)));
typedef u16 u16x4 __attribute__((ext_vector_type(4)));

__device__ __forceinline__ u16 f2bf(float f) {
    u32 u = __float_as_uint(f);
    u32 r = u + 0x7FFFu + ((u >> 16) & 1u);   // round-to-nearest-even
    return (u16)(r >> 16);
}
__device__ __forceinline__ float bf2f(u16 s) {
    return __uint_as_float(((u32)s) << 16);
}
__device__ __forceinline__ float sigmoidf_(float z) {
    return 1.0f / (1.0f + __expf(-z));
}
__device__ __forceinline__ void load_lds16(const void* g, void* l) {
    __builtin_amdgcn_global_load_lds(
        (const __attribute__((address_space(1))) void*)g,
        (__attribute__((address_space(3))) void*)l, 16, 0, 0);
}

// ---------------- weight transpose + cast: Wt[n][k] = bf16(W[k][n]) ----------------
__global__ __launch_bounds__(256) void transpose_cast_kernel(
    const float* __restrict__ W, u16* __restrict__ Wt, int K, int N)
{
    __shared__ float tile[32][33];
    const int bk = blockIdx.x * 32, bn = blockIdx.y * 32;
    const int tx = threadIdx.x, ty = threadIdx.y;   // (32,8)
    #pragma unroll
    for (int i = 0; i < 32; i += 8)
        tile[ty + i][tx] = W[(size_t)(bk + ty + i) * N + bn + tx];
    __syncthreads();
    #pragma unroll
    for (int i = 0; i < 32; i += 8)
        Wt[(size_t)(bn + ty + i) * K + bk + tx] = f2bf(tile[tx][ty + i]);
}

// ============ 256^2 8-phase GEMM mainloop (T2+T3+T4+T5) ============
// A (lda-major), Bt (ldb-major), bf16 row-major.  nkt = K/64 (even, pow2).
// LDS: 8 slots of 16 KiB: slot = buf*4 + {A:0/1, B:2/3} + half.
// Half-tile = 128 rows x 64 k, rows swizzled: row r chunk c holds global
// chunk c^(r&7) (chunk = 16B).  Staged linearly (dst = tid*16 / +8192).
// Wave (wm=wave>>2, wn=wave&3) output: rows wm*128+[0,128) (A-half wm),
// cols wn*64+[0,64) (B-half wn>>1, col offset (wn&1)*64).
// Phase ph=p&3 computes quadrant (a=ph&1, s=ph>>1): rows a*64+[0,64),
// cols s*32+[0,32) of the wave tile, K=64.  Fragments read once/K-tile.
__device__ __forceinline__ void gemm256_mainloop(
    const u16* __restrict__ A, const int lda,
    const u16* __restrict__ Bt, const int ldb, const int nkt,
    const int m0, const int n0, u16* lds, f32x4 acc[2][2][4][2])
{
    const int tid  = threadIdx.x;
    const int wave = tid >> 6, lane = tid & 63;
    const int q = lane >> 4, m16 = lane & 15;
    const int wm = wave >> 2, wn = wave & 3;

    const f32x4 zero4 = {0.f, 0.f, 0.f, 0.f};
    #pragma unroll
    for (int i = 0; i < 2; ++i)
        #pragma unroll
        for (int j = 0; j < 2; ++j)
            #pragma unroll
            for (int k = 0; k < 4; ++k)
                #pragma unroll
                for (int l = 0; l < 2; ++l) acc[i][j][k][l] = zero4;

    // staging geometry: thread covers (row sr, chunk tid&7) and (+64 rows)
    const int sr = tid >> 3;                              // 0..63
    const int kc = ((tid & 7) ^ (sr & 7)) << 3;           // swizzled src chunk (shorts)
    const size_t abase = (size_t)(m0 + sr) * lda + kc;
    const size_t bbase = (size_t)(n0 + sr) * ldb + kc;
    const size_t lda64 = (size_t)lda << 6, ldb64 = (size_t)ldb << 6;
    char* ldsb = (char*)lds;
    const int dst0 = tid << 4;

#define STG_A(bufs, hf, k0) do { \
    char* d_ = ldsb + (((bufs) * 4 + (hf)) << 14) + dst0; \
    const u16* g_ = A + abase + (size_t)(hf) * 2 * lda64 + (k0); \
    load_lds16(g_, d_); load_lds16(g_ + lda64, d_ + 8192); } while (0)
#define STG_B(bufs, hf, k0) do { \
    char* d_ = ldsb + (((bufs) * 4 + 2 + (hf)) << 14) + dst0; \
    const u16* g_ = Bt + bbase + (size_t)(hf) * 2 * ldb64 + (k0); \
    load_lds16(g_, d_); load_lds16(g_ + ldb64, d_ + 8192); } while (0)

    // prologue: buf0 complete (tile0) + b1.A0 (tile1); 10 loads.
    // vmcnt(2): buf0's 8 loads landed (b1.A0 may fly; covered by end-p3).
    STG_A(0, 0, 0);  STG_B(0, 0, 0);  STG_A(0, 1, 0);  STG_B(0, 1, 0);
    STG_A(1, 0, 64);
    asm volatile("s_waitcnt vmcnt(2)" ::: "memory");
    __builtin_amdgcn_s_barrier();

    const int xh = m16 & 7;
    const int ch0 = ((q ^ xh) << 3), ch1 = (((4 + q) ^ xh) << 3);
    const int bcol = (wn & 1) << 6;            // col offset within B-half

    #pragma unroll 1
    for (int kt2 = 0; kt2 < nkt; kt2 += 2) {
        bf16x8 av[2][4][2], bv[2][2][2];       // held fragments (static idx)
        #pragma unroll
        for (int p = 0; p < 8; ++p) {
            const int buf = p >> 2, ph = p & 3;
            const u16* Asl = lds + ((buf * 4 + wm) << 13);
            const u16* Bsl = lds + ((buf * 4 + 2 + (wn >> 1)) << 13);
            if (ph == 0) {
                #pragma unroll
                for (int mf = 0; mf < 4; ++mf) {
                    av[0][mf][0] = *(const bf16x8*)&Asl[(mf * 16 + m16) * 64 + ch0];
                    av[0][mf][1] = *(const bf16x8*)&Asl[(mf * 16 + m16) * 64 + ch1];
                }
                #pragma unroll
                for (int nf = 0; nf < 2; ++nf) {
                    bv[0][nf][0] = *(const bf16x8*)&Bsl[(bcol + nf * 16 + m16) * 64 + ch0];
                    bv[0][nf][1] = *(const bf16x8*)&Bsl[(bcol + nf * 16 + m16) * 64 + ch1];
                }
            } else if (ph == 1) {
                #pragma unroll
                for (int mf = 0; mf < 4; ++mf) {
                    av[1][mf][0] = *(const bf16x8*)&Asl[(64 + mf * 16 + m16) * 64 + ch0];
                    av[1][mf][1] = *(const bf16x8*)&Asl[(64 + mf * 16 + m16) * 64 + ch1];
                }
                #pragma unroll
                for (int nf = 0; nf < 2; ++nf) {
                    bv[1][nf][0] = *(const bf16x8*)&Bsl[(bcol + 32 + nf * 16 + m16) * 64 + ch0];
                    bv[1][nf][1] = *(const bf16x8*)&Bsl[(bcol + 32 + nf * 16 + m16) * 64 + ch1];
                }
            }
            // stage stagger (see header audit; k wraps in tail, unread)
            {
                const int k1 = ((kt2 + 1) & (nkt - 1)) << 6;
                const int k2 = ((kt2 + 2) & (nkt - 1)) << 6;
                const int k3 = ((kt2 + 3) & (nkt - 1)) << 6;
                if (p == 0)      STG_B(1, 0, k1);   // b1.B0 <- t+1
                else if (p == 1) STG_A(1, 1, k1);   // b1.A1 <- t+1
                else if (p == 2) STG_B(1, 1, k1);   // b1.B1 <- t+1
                else if (p == 3) STG_A(0, 0, k2);   // b0.A0 <- t+2
                else if (p == 4) STG_B(0, 0, k2);   // b0.B0 <- t+2
                else if (p == 5) STG_A(0, 1, k2);   // b0.A1 <- t+2
                else if (p == 6) STG_B(0, 1, k2);   // b0.B1 <- t+2
                else             STG_A(1, 0, k3);   // b1.A0 <- t+3
            }
            __builtin_amdgcn_s_barrier();
            if (ph == 1) asm volatile("s_waitcnt lgkmcnt(4)" ::: "memory");
            else         asm volatile("s_waitcnt lgkmcnt(0)" ::: "memory");
            __builtin_amdgcn_s_setprio(1);
            {
                const int a = ph & 1, s = ph >> 1;
                #pragma unroll
                for (int mf = 0; mf < 4; ++mf)
                    #pragma unroll
                    for (int nf = 0; nf < 2; ++nf) {
                        acc[a][s][mf][nf] = __builtin_amdgcn_mfma_f32_16x16x32_bf16(
                            av[a][mf][0], bv[s][nf][0], acc[a][s][mf][nf], 0, 0, 0);
                        acc[a][s][mf][nf] = __builtin_amdgcn_mfma_f32_16x16x32_bf16(
                            av[a][mf][1], bv[s][nf][1], acc[a][s][mf][nf], 0, 0, 0);
                    }
            }
            __builtin_amdgcn_s_setprio(0);
            // end-p3: waits {p7-prev,p0,p1,p2} = buf1 halves (read p4/p5)
            // end-p7: waits {p3,p4,p5,p6} = buf0 halves (read next p0/p1)
            if (ph == 3) asm volatile("s_waitcnt vmcnt(2)" ::: "memory");
            __builtin_amdgcn_s_barrier();
        }
    }
    // drain DMA before LDS dealloc / epilogue
    asm volatile("s_waitcnt vmcnt(0)" ::: "memory");
#undef STG_A
#undef STG_B
}

// ---------------- LN1: xn = LN(x,g1,b1) as bf16 ----------------
__global__ __launch_bounds__(256) void ln1_kernel(
    const float* __restrict__ x, const float* __restrict__ g, const float* __restrict__ b,
    u16* __restrict__ xn)
{
    const int row = blockIdx.x, tid = threadIdx.x;
    const size_t base = (size_t)row * C;
    const int c = tid * 4;
    float4 v = *(const float4*)&x[base + c];
    float s  = v.x + v.y + v.z + v.w;
    float s2 = v.x*v.x + v.y*v.y + v.z*v.z + v.w*v.w;
    #pragma unroll
    for (int off = 32; off >= 1; off >>= 1) { s += __shfl_xor(s, off); s2 += __shfl_xor(s2, off); }
    __shared__ float red[8];
    const int wave = tid >> 6, lane = tid & 63;
    if (lane == 0) { red[wave] = s; red[4 + wave] = s2; }
    __syncthreads();
    const float sum  = red[0] + red[1] + red[2] + red[3];
    const float sums = red[4] + red[5] + red[6] + red[7];
    const float mean = sum * (1.0f / C);
    const float var  = sums * (1.0f / C) - mean * mean;
    const float rstd = rsqrtf(var + 1e-5f);
    float4 gv = *(const float4*)&g[c];
    float4 bv = *(const float4*)&b[c];
    u16x4 o;
    o.x = f2bf((v.x - mean) * rstd * gv.x + bv.x);
    o.y = f2bf((v.y - mean) * rstd * gv.y + bv.y);
    o.z = f2bf((v.z - mean) * rstd * gv.z + bv.z);
    o.w = f2bf((v.w - mean) * rstd * gv.w + bv.w);
    *(u16x4*)&xn[base + c] = o;
}

// ---------------- GEMM1 + time-mix epilogue -> packed kv (dword) + r (bf16) ----------------
__global__ __launch_bounds__(512, 2) void gemm1_kernel(
    const u16* __restrict__ xn, const u16* __restrict__ wt,
    const float* __restrict__ x,
    const float* __restrict__ tmk, const float* __restrict__ tmv, const float* __restrict__ tmr,
    u16* __restrict__ kvbuf, u16* __restrict__ rbuf)
{
    __shared__ __align__(16) u16 lds[8 * 8192];   // 128 KiB
    f32x4 acc[2][2][4][2];
    const int nbn = 12;
    int id = blockIdx.x;
    id = (id & 7) * (768 >> 3) + (id >> 3);       // XCD-aware swizzle (768 % 8 == 0)
    const int m0 = (id / nbn) << 8, n0 = (id % nbn) << 8;
    gemm256_mainloop(xn, C, wt, C, 16, m0, n0, lds, acc);

    const int tid = threadIdx.x, wave = tid >> 6, lane = tid & 63;
    const int q = lane >> 4, m16 = lane & 15;
    const int wm = wave >> 2, wn = wave & 3;
    const int grp = n0 >> 10;                     // 0=k, 1=v, 2=r (uniform per block)
    #pragma unroll
    for (int a = 0; a < 2; ++a)
    #pragma unroll
    for (int mf = 0; mf < 4; ++mf)
    #pragma unroll
    for (int rg = 0; rg < 4; ++rg) {
        const int row = m0 + wm * 128 + a * 64 + mf * 16 + q * 4 + rg;
        const int t = row & (T - 1);
        const size_t rowp = (size_t)(t ? row - 1 : row) * C;   // time-mix x_prev row
        #pragma unroll
        for (int s = 0; s < 2; ++s)
        #pragma unroll
        for (int nf = 0; nf < 2; ++nf) {
            const int cc = (n0 + wn * 64 + s * 32 + nf * 16 + m16) & (C - 1);
            const float val = acc[a][s][mf][nf][rg];
            const float xp = x[rowp + cc];
            if (grp == 0) {
                const float f = tmk[cc];
                kvbuf[(size_t)row * 2048 + 2 * cc] = f2bf(val * f + xp * (1.0f - f));
            } else if (grp == 1) {
                const float f = tmv[cc];
                kvbuf[(size_t)row * 2048 + 2 * cc + 1] = f2bf(val * f + xp * (1.0f - f));
            } else {
                const float f = tmr[cc];
                rbuf[(size_t)row * C + cc] = f2bf(sigmoidf_(val * f + xp * (1.0f - f)));
            }
        }
    }
}

// ================= WKV chunked parallel scan =================
__global__ __launch_bounds__(256) void wkv_k1(
    const u32* __restrict__ kvp, const float* __restrict__ wdec, float* __restrict__ bc)
{
    const int tid = blockIdx.x * 256 + threadIdx.x;
    const int c = tid & (C - 1), ci = tid >> 10;
    const float w = wdec[c];
    const size_t L = ((size_t)(ci >> 6) * T + (size_t)(ci & (NCH - 1)) * LCH) * C + c;
    float bb = -1e38f;
    #pragma unroll 4
    for (int t = 0; t < LCH; ++t) {
        const float k = bf2f((u16)(kvp[L + (size_t)t * C] & 0xffffu));
        const float ww = w + bb;
        const float p = fmaxf(ww, k);
        const float e1 = __expf(ww - p), e2 = __expf(k - p);
        bb = p + __logf(e1 + e2 + 1e-8f);
    }
    bc[tid] = bb;
}

__global__ __launch_bounds__(256) void wkv_p1(
    const float* __restrict__ bc, const float* __restrict__ wdec, float* __restrict__ bbin)
{
    const int gid = blockIdx.x * 256 + threadIdx.x;   // 0..8191 = b*C + c
    const int c = gid & (C - 1), b = gid >> 10;
    const float Lw = (float)LCH * wdec[c];
    float bb = -1e38f;
    #pragma unroll 8
    for (int j = 0; j < NCH; ++j) {
        const int idx = (b * NCH + j) * C + c;
        bbin[idx] = bb;
        const float a = Lw + bb;
        const float bcv = bc[idx];
        const float m = fmaxf(a, bcv);
        bb = m + __logf(__expf(a - m) + __expf(bcv - m));
    }
}

__global__ __launch_bounds__(256) void wkv_k2a(
    const u32* __restrict__ kvp, const float* __restrict__ wdec,
    const float* __restrict__ bbin, float* __restrict__ logS, float* __restrict__ Rr)
{
    const int tid = blockIdx.x * 256 + threadIdx.x;
    const int c = tid & (C - 1), ci = tid >> 10;
    const float w = wdec[c];
    const size_t L = ((size_t)(ci >> 6) * T + (size_t)(ci & (NCH - 1)) * LCH) * C + c;
    float bb = bbin[tid], ls = 0.0f, R = 0.0f;
    #pragma unroll 4
    for (int t = 0; t < LCH; ++t) {
        const u32 kv = kvp[L + (size_t)t * C];
        const float k = bf2f((u16)(kv & 0xffffu)), v = bf2f((u16)(kv >> 16));
        const float ww = w + bb;
        const float p = fmaxf(ww, k);
        const float e1 = __expf(ww - p), e2 = __expf(k - p);
        R = e1 * R + e2 * v;
        ls += ww - p;                       // log of alpha product (<=0)
        bb = p + __logf(e1 + e2 + 1e-8f);
    }
    logS[tid] = ls;
    Rr[tid] = R;
}

__global__ __launch_bounds__(256) void wkv_p2(
    const float* __restrict__ logS, const float* __restrict__ Rr, float* __restrict__ aain)
{
    const int gid = blockIdx.x * 256 + threadIdx.x;   // b*C + c
    const int c = gid & (C - 1), b = gid >> 10;
    float a = 0.0f;
    #pragma unroll 8
    for (int j = 0; j < NCH; ++j) {
        const int idx = (b * NCH + j) * C + c;
        aain[idx] = a;
        a = __expf(logS[idx]) * a + Rr[idx];
    }
}

__global__ __launch_bounds__(256) void wkv_k2c(
    const u32* __restrict__ kvp, const u16* __restrict__ rbuf, const float* __restrict__ x,
    const float* __restrict__ wdec, const float* __restrict__ ufirst,
    const float* __restrict__ bbin, const float* __restrict__ aain,
    float* __restrict__ x2, float* __restrict__ state)
{
    const int tid = blockIdx.x * 256 + threadIdx.x;
    const int c = tid & (C - 1), ci = tid >> 10;
    const int b = ci >> 6, j = ci & (NCH - 1);
    const float w = wdec[c], u = ufirst[c];
    float aa = aain[tid], bb = bbin[tid];
    const size_t L = ((size_t)b * T + (size_t)j * LCH) * C + c;
    #pragma unroll 4
    for (int t = 0; t < LCH; ++t) {
        const size_t idx = L + (size_t)t * C;
        const u32 kv = kvp[idx];
        const float k = bf2f((u16)(kv & 0xffffu)), v = bf2f((u16)(kv >> 16));
        const float r = bf2f(rbuf[idx]), xv = x[idx];
        float ww = u + k;
        float p  = fmaxf(bb, ww);
        float e1 = __expf(bb - p), e2 = __expf(ww - p);
        const float y = (e1 * aa + e2 * v) / (e1 + e2 + 1e-8f);
        x2[idx] = xv + r * y;
        ww = w + bb;
        p  = fmaxf(ww, k);
        e1 = __expf(ww - p); e2 = __expf(k - p);
        aa = e1 * aa + e2 * v;
        bb = p + __logf(e1 + e2 + 1e-8f);
    }
    if (j == NCH - 1) {
        state[2 * (b * C + c)]     = aa;
        state[2 * (b * C + c) + 1] = bb;
    }
}

// ---------------- LN2 + rr + xp_s snapshot ----------------
__global__ __launch_bounds__(256) void ln2_kernel(
    const float* __restrict__ x2, const float* __restrict__ g, const float* __restrict__ b,
    const float* __restrict__ cmr, u16* __restrict__ xn, u16* __restrict__ rr,
    u16* __restrict__ xps)
{
    const int row = blockIdx.x, tid = threadIdx.x;
    const size_t base = (size_t)row * C;
    const int t = row & (T - 1);
    const size_t basep = (size_t)(row - t + (t ? t - 1 : T - 1)) * C;   // cm xp row (wraps)
    const int c = tid * 4;
    float4 v = *(const float4*)&x2[base + c];
    float s  = v.x + v.y + v.z + v.w;
    float s2 = v.x*v.x + v.y*v.y + v.z*v.z + v.w*v.w;
    #pragma unroll
    for (int off = 32; off >= 1; off >>= 1) { s += __shfl_xor(s, off); s2 += __shfl_xor(s2, off); }
    __shared__ float red[8];
    const int wave = tid >> 6, lane = tid & 63;
    if (lane == 0) { red[wave] = s; red[4 + wave] = s2; }
    __syncthreads();
    const float sum  = red[0] + red[1] + red[2] + red[3];
    const float sums = red[4] + red[5] + red[6] + red[7];
    const float mean = sum * (1.0f / C);
    const float var  = sums * (1.0f / C) - mean * mean;
    const float rstd = rsqrtf(var + 1e-5f);
    float4 gv = *(const float4*)&g[c];
    float4 bv = *(const float4*)&b[c];
    float4 fv = *(const float4*)&cmr[c];
    float4 xp = *(const float4*)&x2[basep + c];
    float xn0 = (v.x - mean) * rstd * gv.x + bv.x;
    float xn1 = (v.y - mean) * rstd * gv.y + bv.y;
    float xn2 = (v.z - mean) * rstd * gv.z + bv.z;
    float xn3 = (v.w - mean) * rstd * gv.w + bv.w;
    u16x4 o; o.x = f2bf(xn0); o.y = f2bf(xn1); o.z = f2bf(xn2); o.w = f2bf(xn3);
    *(u16x4*)&xn[base + c] = o;
    u16x4 p4; p4.x = f2bf(xp.x); p4.y = f2bf(xp.y); p4.z = f2bf(xp.z); p4.w = f2bf(xp.w);
    *(u16x4*)&xps[base + c] = p4;
    u16x4 r4;
    r4.x = f2bf(sigmoidf_(xn0 * fv.x + xp.x * (1.0f - fv.x)));
    r4.y = f2bf(sigmoidf_(xn1 * fv.y + xp.y * (1.0f - fv.y)));
    r4.z = f2bf(sigmoidf_(xn2 * fv.z + xp.z * (1.0f - fv.z)));
    r4.w = f2bf(sigmoidf_(xn3 * fv.w + xp.w * (1.0f - fv.w)));
    *(u16x4*)&rr[base + c] = r4;
}

// ---------------- GEMM2 (one 2048-col half) + cm-mix + relu^2 -> h_half (bf16) ----------------
__global__ __launch_bounds__(512, 2) void gemm2_kernel(
    const u16* __restrict__ xn, const u16* __restrict__ wt,   // wt pre-offset to half
    const u16* __restrict__ xps, const float* __restrict__ cmk,
    u16* __restrict__ hbuf, const int nbase)
{
    __shared__ __align__(16) u16 lds[8 * 8192];
    f32x4 acc[2][2][4][2];
    const int nbn = 8;
    int id = blockIdx.x;
    id = (id & 7) * (512 >> 3) + (id >> 3);
    const int m0 = (id / nbn) << 8, n0 = (id % nbn) << 8;
    gemm256_mainloop(xn, C, wt, C, 16, m0, n0, lds, acc);

    const int tid = threadIdx.x, wave = tid >> 6, lane = tid & 63;
    const int q = lane >> 4, m16 = lane & 15;
    const int wm = wave >> 2, wn = wave & 3;
    #pragma unroll
    for (int a = 0; a < 2; ++a)
    #pragma unroll
    for (int mf = 0; mf < 4; ++mf)
    #pragma unroll
    for (int rg = 0; rg < 4; ++rg) {
        const int row = m0 + wm * 128 + a * 64 + mf * 16 + q * 4 + rg;
        #pragma unroll
        for (int s = 0; s < 2; ++s)
        #pragma unroll
        for (int nf = 0; nf < 2; ++nf) {
            const int nloc = n0 + wn * 64 + s * 32 + nf * 16 + m16;  // 0..2047
            const int cc = (nbase + nloc) & (C - 1);
            const float f = cmk[cc];
            const float xp = bf2f(xps[(size_t)row * C + cc]);
            const float kk = acc[a][s][mf][nf][rg] * f + xp * (1.0f - f);
            const float h = fmaxf(kk, 0.0f);
            hbuf[(size_t)row * 2048 + nloc] = f2bf(h * h);
        }
    }
}

// ---------------- GEMM3 (K=2048 half) + residual epilogue, accumulates into out ----------------
__global__ __launch_bounds__(512, 2) void gemm3_kernel(
    const u16* __restrict__ hbuf, const u16* __restrict__ wt,  // wt pre-offset to half
    const u16* __restrict__ rr, float* __restrict__ out)
{
    __shared__ __align__(16) u16 lds[8 * 8192];
    f32x4 acc[2][2][4][2];
    const int nbn = 4;
    int id = blockIdx.x;
    id = (id & 7) * (256 >> 3) + (id >> 3);
    const int m0 = (id / nbn) << 8, n0 = (id % nbn) << 8;
    gemm256_mainloop(hbuf, 2048, wt, 4096, 32, m0, n0, lds, acc);

    const int tid = threadIdx.x, wave = tid >> 6, lane = tid & 63;
    const int q = lane >> 4, m16 = lane & 15;
    const int wm = wave >> 2, wn = wave & 3;
    #pragma unroll
    for (int a = 0; a < 2; ++a)
    #pragma unroll
    for (int mf = 0; mf < 4; ++mf)
    #pragma unroll
    for (int rg = 0; rg < 4; ++rg) {
        const int row = m0 + wm * 128 + a * 64 + mf * 16 + q * 4 + rg;
        #pragma unroll
        for (int s = 0; s < 2; ++s)
        #pragma unroll
        for (int nf = 0; nf < 2; ++nf) {
            const int cc = n0 + wn * 64 + s * 32 + nf * 16 + m16;
            const size_t idx = (size_t)row * C + cc;
            const float base = out[idx];   // pass0: x2; pass1: partial result
            out[idx] = base + bf2f(rr[idx]) * acc[a][s][mf][nf][rg];
        }
    }
}

// ---------------- workspace layout (byte offsets), total 176 MB ----------------
#define OFF_WT_CM  0            //  8 MB  (4096 x 1024 bf16)
#define OFF_WT_CP  8388608      //  8 MB  (1024 x 4096 bf16)
#define OFF_XN     16777216     // 32 MB  (M x C bf16; LN1 then LN2)
#define OFF_KV     50331648     // 64 MB  (M x C packed (k,v) bf16 pairs)
#define OFF_H      OFF_KV       // 64 MB  (M x 2048 bf16 half; overlays kv, dead after wkv)
#define OFF_RB     117440512    // 32 MB  (bf16; reused as rr after wkv)
#define OFF_WT_TM  150994944    //  6 MB  (3072 x 1024 bf16; dead after gemm1)
// wkv scratch overlays the wt_tm/xps extent during the scan (dead then):
#define OFF_BC     150994944    // 2 MB
#define OFF_BBIN   153092096    // 2 MB
#define OFF_LOGS   155189248    // 2 MB
#define OFF_RCH    157286400    // 2 MB
#define OFF_AAIN   159383552    // 2 MB
#define OFF_XPS    150994944    // 32 MB (bf16 shifted x2; born at ln2, after wkv)

extern "C" void kernel_launch(void* const* d_in, const int* in_sizes, int n_in,
                              void* d_out, int out_size, void* d_ws, size_t ws_size,
                              hipStream_t stream) {
    const float* x          = (const float*)d_in[0];
    const float* time_decay = (const float*)d_in[1];
    const float* time_first = (const float*)d_in[2];
    const float* W_tm       = (const float*)d_in[3];
    const float* g1         = (const float*)d_in[4];
    const float* b1         = (const float*)d_in[5];
    const float* tmk        = (const float*)d_in[6];
    const float* tmv        = (const float*)d_in[7];
    const float* tmr        = (const float*)d_in[8];
    const float* W_cm       = (const float*)d_in[9];
    const float* W_cp       = (const float*)d_in[10];
    const float* g2         = (const float*)d_in[11];
    const float* b2         = (const float*)d_in[12];
    const float* cmk        = (const float*)d_in[13];
    const float* cmr        = (const float*)d_in[14];
    float* out = (float*)d_out;

    char* ws = (char*)d_ws;
    u16*   wt_cm = (u16*)(ws + OFF_WT_CM);
    u16*   wt_cp = (u16*)(ws + OFF_WT_CP);
    u16*   xn    = (u16*)(ws + OFF_XN);
    u16*   kvbuf = (u16*)(ws + OFF_KV);
    u16*   hbuf  = (u16*)(ws + OFF_H);
    u16*   rbuf  = (u16*)(ws + OFF_RB);   // rr reuses this after wkv
    u16*   wt_tm = (u16*)(ws + OFF_WT_TM);
    u16*   xps   = (u16*)(ws + OFF_XPS);
    float* bc    = (float*)(ws + OFF_BC);
    float* bbin  = (float*)(ws + OFF_BBIN);
    float* logS  = (float*)(ws + OFF_LOGS);
    float* Rch   = (float*)(ws + OFF_RCH);
    float* aain  = (float*)(ws + OFF_AAIN);
    float* x2    = out;                    // residual stream lives in d_out

    // 1. weights -> bf16 B^T
    transpose_cast_kernel<<<dim3(1024/32, 3072/32), dim3(32, 8), 0, stream>>>(W_tm, wt_tm, 1024, 3072);
    transpose_cast_kernel<<<dim3(1024/32, 4096/32), dim3(32, 8), 0, stream>>>(W_cm, wt_cm, 1024, 4096);
    transpose_cast_kernel<<<dim3(4096/32, 1024/32), dim3(32, 8), 0, stream>>>(W_cp, wt_cp, 4096, 1024);
    // 2. LN1
    ln1_kernel<<<M, 256, 0, stream>>>(x, g1, b1, xn);
    // 3. GEMM1 + time-mix (256^2 8-phase; 768 blocks)
    gemm1_kernel<<<768, 512, 0, stream>>>(xn, wt_tm, x, tmk, tmv, tmr, kvbuf, rbuf);
    // 4. WKV chunked parallel scan (x2 -> d_out body, state -> d_out tail)
    {
        const u32* kvp = (const u32*)kvbuf;
        wkv_k1 <<<WKV_THREADS/256, 256, 0, stream>>>(kvp, time_decay, bc);
        wkv_p1 <<<(Bb*C)/256, 256, 0, stream>>>(bc, time_decay, bbin);
        wkv_k2a<<<WKV_THREADS/256, 256, 0, stream>>>(kvp, time_decay, bbin, logS, Rch);
        wkv_p2 <<<(Bb*C)/256, 256, 0, stream>>>(logS, Rch, aain);
        wkv_k2c<<<WKV_THREADS/256, 256, 0, stream>>>(kvp, rbuf, x, time_decay, time_first,
                                                     bbin, aain, x2, out + (size_t)M * C);
    }
    // 5. LN2 + rr + xp snapshot
    ln2_kernel<<<M, 256, 0, stream>>>(x2, g2, b2, cmr, xn, rbuf, xps);
    // 6+7. channel-mix GEMMs in two hidden-halves (h_half overlays dead kv)
    for (int half = 0; half < 2; ++half) {
        const int nbase = half * 2048;
        gemm2_kernel<<<512, 512, 0, stream>>>(
            xn, wt_cm + (size_t)nbase * C, xps, cmk, hbuf, nbase);
        gemm3_kernel<<<256, 512, 0, stream>>>(
            hbuf, wt_cp + nbase, rbuf, out);
    }
}

// Round 7
// 845.505 us; speedup vs baseline: 1.9105x; 1.9105x over previous
//
#include <hip/hip_runtime.h>

// RWKV block on MI355X (gfx950).  B=8, T=2048, C=1024, M=16384.
// R9 (resubmit; R6 bench was an infra failure, kernel never ran):
//     fixed R8's register spills.  R8 kept 24 bf16x8 fragments (96 VGPR)
//     live across all 8 phases + 128 acc regs -> spilled to scratch
//     (FETCH +100MB, WRITE +100MB, dur 225->342us).  New phase layout
//     keeps <=64 fragment VGPRs live:
//       ph0: read av0(8)+bv0(4); MFMA(a0,s0)
//       ph1: read bv1(4);        MFMA(a0,s1)   [av0 dies]
//       ph2: read av1(8);        MFMA(a1,s0)   [bv0 dies]
//       ph3: (no reads)          MFMA(a1,s1)
//     Stages, 2 halves/phase (16 loads/iter):
//       p0: b1.B0+B1 <- t+1 | p3: b0.A0+A1 <- t+2 | p4: b0.B0+B1 <- t+2
//       p7: b1.A0+A1 <- t+3
//     Overwrite audit: staged region's old contents last drained >=1
//     barrier earlier (b0.A drains p2-lgkm, b0.B p1, b1.A p6, b1.B prev-p5).
//     Landing: end-p3 vmcnt(4) (prev-p7+p0 landed => buf1 ok for p4);
//     end-p7 vmcnt(4) (p3+p4 landed => buf0 ok for next p0); 3-phase lags.
//     Prologue: b0 all + b1.A (12 loads), vmcnt(4).
//     R7 model validated: 2800cy/phase = 192 b128/CU/phase x 12cy serialized;
//     R9 cuts LDS reads to 24/wave/K-tile (floor ~94us for gemm1).
// R5-R8: 256^2 8-phase schedule, BK=64, 8 waves (2Mx4N contiguous wave
//     tiles 128x64), 128 KiB LDS dbuf, raw s_barrier, setprio, XOR-chunk
//     swizzle.  WKV: chunked parallel scan (R3).

#define Bb 8
#define T 2048
#define C 1024
#define M (Bb*T)
#define LCH 32            // chunk length
#define NCH 64            // chunks per sequence (T/LCH)
#define NCI (Bb*NCH)      // 512 chunk instances
#define WKV_THREADS (NCI*C)   // 524288

typedef unsigned short u16;
typedef unsigned int u32;
typedef __bf16 bf16x8 __attribute__((ext_vector_type(8)));
typedef float f32x4 __attribute__((ext_vector_type(4)));
typedef u16 u16x4 __attribute__((ext_vector_type(4)));

__device__ __forceinline__ u16 f2bf(float f) {
    u32 u = __float_as_uint(f);
    u32 r = u + 0x7FFFu + ((u >> 16) & 1u);   // round-to-nearest-even
    return (u16)(r >> 16);
}
__device__ __forceinline__ float bf2f(u16 s) {
    return __uint_as_float(((u32)s) << 16);
}
__device__ __forceinline__ float sigmoidf_(float z) {
    return 1.0f / (1.0f + __expf(-z));
}
__device__ __forceinline__ void load_lds16(const void* g, void* l) {
    __builtin_amdgcn_global_load_lds(
        (const __attribute__((address_space(1))) void*)g,
        (__attribute__((address_space(3))) void*)l, 16, 0, 0);
}

// ---------------- weight transpose + cast: Wt[n][k] = bf16(W[k][n]) ----------------
__global__ __launch_bounds__(256) void transpose_cast_kernel(
    const float* __restrict__ W, u16* __restrict__ Wt, int K, int N)
{
    __shared__ float tile[32][33];
    const int bk = blockIdx.x * 32, bn = blockIdx.y * 32;
    const int tx = threadIdx.x, ty = threadIdx.y;   // (32,8)
    #pragma unroll
    for (int i = 0; i < 32; i += 8)
        tile[ty + i][tx] = W[(size_t)(bk + ty + i) * N + bn + tx];
    __syncthreads();
    #pragma unroll
    for (int i = 0; i < 32; i += 8)
        Wt[(size_t)(bn + ty + i) * K + bk + tx] = f2bf(tile[tx][ty + i]);
}

// ============ 256^2 8-phase GEMM mainloop (T2+T3+T4+T5) ============
// A (lda-major), Bt (ldb-major), bf16 row-major.  nkt = K/64 (even, pow2).
// LDS: 8 slots of 16 KiB: slot = buf*4 + {A:0/1, B:2/3} + half.
// Half-tile = 128 rows x 64 k, rows swizzled: row r chunk c holds global
// chunk c^(r&7) (chunk = 16B).  Staged linearly (dst = tid*16 / +8192).
// Wave (wm=wave>>2, wn=wave&3) output: rows wm*128+[0,128) (A-half wm),
// cols wn*64+[0,64) (B-half wn>>1, col offset (wn&1)*64).
// Phase ph computes (a,s) = (ph>>1, ph&1): rows a*64+[0,64),
// cols s*32+[0,32) of the wave tile, K=64.  Fragments read once/K-tile.
__device__ __forceinline__ void gemm256_mainloop(
    const u16* __restrict__ A, const int lda,
    const u16* __restrict__ Bt, const int ldb, const int nkt,
    const int m0, const int n0, u16* lds, f32x4 acc[2][2][4][2])
{
    const int tid  = threadIdx.x;
    const int wave = tid >> 6, lane = tid & 63;
    const int q = lane >> 4, m16 = lane & 15;
    const int wm = wave >> 2, wn = wave & 3;

    const f32x4 zero4 = {0.f, 0.f, 0.f, 0.f};
    #pragma unroll
    for (int i = 0; i < 2; ++i)
        #pragma unroll
        for (int j = 0; j < 2; ++j)
            #pragma unroll
            for (int k = 0; k < 4; ++k)
                #pragma unroll
                for (int l = 0; l < 2; ++l) acc[i][j][k][l] = zero4;

    // staging geometry: thread covers (row sr, chunk tid&7) and (+64 rows)
    const int sr = tid >> 3;                              // 0..63
    const int kc = ((tid & 7) ^ (sr & 7)) << 3;           // swizzled src chunk (shorts)
    const size_t abase = (size_t)(m0 + sr) * lda + kc;
    const size_t bbase = (size_t)(n0 + sr) * ldb + kc;
    const size_t lda64 = (size_t)lda << 6, ldb64 = (size_t)ldb << 6;
    char* ldsb = (char*)lds;
    const int dst0 = tid << 4;

#define STG_A(bufs, hf, k0) do { \
    char* d_ = ldsb + (((bufs) * 4 + (hf)) << 14) + dst0; \
    const u16* g_ = A + abase + (size_t)(hf) * 2 * lda64 + (k0); \
    load_lds16(g_, d_); load_lds16(g_ + lda64, d_ + 8192); } while (0)
#define STG_B(bufs, hf, k0) do { \
    char* d_ = ldsb + (((bufs) * 4 + 2 + (hf)) << 14) + dst0; \
    const u16* g_ = Bt + bbase + (size_t)(hf) * 2 * ldb64 + (k0); \
    load_lds16(g_, d_); load_lds16(g_ + ldb64, d_ + 8192); } while (0)

    // prologue: buf0 complete (tile0, 8 loads) + b1.A0/A1 (tile1, 4 loads).
    // vmcnt(4): buf0 landed; b1.A in flight (covered by end-p3 wait).
    STG_A(0, 0, 0);  STG_A(0, 1, 0);  STG_B(0, 0, 0);  STG_B(0, 1, 0);
    STG_A(1, 0, 64); STG_A(1, 1, 64);
    asm volatile("s_waitcnt vmcnt(4)" ::: "memory");
    __builtin_amdgcn_s_barrier();

    const int xh = m16 & 7;
    const int ch0 = ((q ^ xh) << 3), ch1 = (((4 + q) ^ xh) << 3);
    const int bcol = (wn & 1) << 6;            // col offset within B-half

#define MMBLK(AV, BV, a, s) do { \
    _Pragma("unroll") \
    for (int mf = 0; mf < 4; ++mf) \
        _Pragma("unroll") \
        for (int nf = 0; nf < 2; ++nf) { \
            acc[a][s][mf][nf] = __builtin_amdgcn_mfma_f32_16x16x32_bf16( \
                AV[mf][0], BV[nf][0], acc[a][s][mf][nf], 0, 0, 0); \
            acc[a][s][mf][nf] = __builtin_amdgcn_mfma_f32_16x16x32_bf16( \
                AV[mf][1], BV[nf][1], acc[a][s][mf][nf], 0, 0, 0); \
        } } while (0)

    #pragma unroll 1
    for (int kt2 = 0; kt2 < nkt; kt2 += 2) {
        bf16x8 av0[4][2], av1[4][2], bv0[2][2], bv1[2][2];
        #pragma unroll
        for (int p = 0; p < 8; ++p) {
            const int buf = p >> 2, ph = p & 3;
            const u16* Asl = lds + ((buf * 4 + wm) << 13);
            const u16* Bsl = lds + ((buf * 4 + 2 + (wn >> 1)) << 13);
            if (ph == 0) {
                #pragma unroll
                for (int mf = 0; mf < 4; ++mf) {
                    av0[mf][0] = *(const bf16x8*)&Asl[(mf * 16 + m16) * 64 + ch0];
                    av0[mf][1] = *(const bf16x8*)&Asl[(mf * 16 + m16) * 64 + ch1];
                }
                #pragma unroll
                for (int nf = 0; nf < 2; ++nf) {
                    bv0[nf][0] = *(const bf16x8*)&Bsl[(bcol + nf * 16 + m16) * 64 + ch0];
                    bv0[nf][1] = *(const bf16x8*)&Bsl[(bcol + nf * 16 + m16) * 64 + ch1];
                }
            } else if (ph == 1) {
                #pragma unroll
                for (int nf = 0; nf < 2; ++nf) {
                    bv1[nf][0] = *(const bf16x8*)&Bsl[(bcol + 32 + nf * 16 + m16) * 64 + ch0];
                    bv1[nf][1] = *(const bf16x8*)&Bsl[(bcol + 32 + nf * 16 + m16) * 64 + ch1];
                }
            } else if (ph == 2) {
                #pragma unroll
                for (int mf = 0; mf < 4; ++mf) {
                    av1[mf][0] = *(const bf16x8*)&Asl[(64 + mf * 16 + m16) * 64 + ch0];
                    av1[mf][1] = *(const bf16x8*)&Asl[(64 + mf * 16 + m16) * 64 + ch1];
                }
            }
            // stages: 2 halves per staging phase (see header audit)
            {
                const int k1 = (kt2 + 1) << 6;
                const int k2 = ((kt2 + 2) & (nkt - 1)) << 6;
                const int k3 = ((kt2 + 3) & (nkt - 1)) << 6;
                if (p == 0)      { STG_B(1, 0, k1); STG_B(1, 1, k1); }
                else if (p == 3) { STG_A(0, 0, k2); STG_A(0, 1, k2); }
                else if (p == 4) { STG_B(0, 0, k2); STG_B(0, 1, k2); }
                else if (p == 7) { STG_A(1, 0, k3); STG_A(1, 1, k3); }
            }
            __builtin_amdgcn_s_barrier();
            if (ph != 3) asm volatile("s_waitcnt lgkmcnt(0)" ::: "memory");
            __builtin_amdgcn_s_setprio(1);
            if (ph == 0)      MMBLK(av0, bv0, 0, 0);
            else if (ph == 1) MMBLK(av0, bv1, 0, 1);
            else if (ph == 2) MMBLK(av1, bv0, 1, 0);
            else              MMBLK(av1, bv1, 1, 1);
            __builtin_amdgcn_s_setprio(0);
            if (ph == 3) asm volatile("s_waitcnt vmcnt(4)" ::: "memory");
            __builtin_amdgcn_s_barrier();
        }
    }
    // drain DMA before LDS dealloc / epilogue
    asm volatile("s_waitcnt vmcnt(0)" ::: "memory");
#undef MMBLK
#undef STG_A
#undef STG_B
}

// ---------------- LN1: xn = LN(x,g1,b1) as bf16 ----------------
__global__ __launch_bounds__(256) void ln1_kernel(
    const float* __restrict__ x, const float* __restrict__ g, const float* __restrict__ b,
    u16* __restrict__ xn)
{
    const int row = blockIdx.x, tid = threadIdx.x;
    const size_t base = (size_t)row * C;
    const int c = tid * 4;
    float4 v = *(const float4*)&x[base + c];
    float s  = v.x + v.y + v.z + v.w;
    float s2 = v.x*v.x + v.y*v.y + v.z*v.z + v.w*v.w;
    #pragma unroll
    for (int off = 32; off >= 1; off >>= 1) { s += __shfl_xor(s, off); s2 += __shfl_xor(s2, off); }
    __shared__ float red[8];
    const int wave = tid >> 6, lane = tid & 63;
    if (lane == 0) { red[wave] = s; red[4 + wave] = s2; }
    __syncthreads();
    const float sum  = red[0] + red[1] + red[2] + red[3];
    const float sums = red[4] + red[5] + red[6] + red[7];
    const float mean = sum * (1.0f / C);
    const float var  = sums * (1.0f / C) - mean * mean;
    const float rstd = rsqrtf(var + 1e-5f);
    float4 gv = *(const float4*)&g[c];
    float4 bv = *(const float4*)&b[c];
    u16x4 o;
    o.x = f2bf((v.x - mean) * rstd * gv.x + bv.x);
    o.y = f2bf((v.y - mean) * rstd * gv.y + bv.y);
    o.z = f2bf((v.z - mean) * rstd * gv.z + bv.z);
    o.w = f2bf((v.w - mean) * rstd * gv.w + bv.w);
    *(u16x4*)&xn[base + c] = o;
}

// ---------------- GEMM1 + time-mix epilogue -> packed kv (dword) + r (bf16) ----------------
__global__ __launch_bounds__(512, 2) void gemm1_kernel(
    const u16* __restrict__ xn, const u16* __restrict__ wt,
    const float* __restrict__ x,
    const float* __restrict__ tmk, const float* __restrict__ tmv, const float* __restrict__ tmr,
    u16* __restrict__ kvbuf, u16* __restrict__ rbuf)
{
    __shared__ __align__(16) u16 lds[8 * 8192];   // 128 KiB
    f32x4 acc[2][2][4][2];
    const int nbn = 12;
    int id = blockIdx.x;
    id = (id & 7) * (768 >> 3) + (id >> 3);       // XCD-aware swizzle (768 % 8 == 0)
    const int m0 = (id / nbn) << 8, n0 = (id % nbn) << 8;
    gemm256_mainloop(xn, C, wt, C, 16, m0, n0, lds, acc);

    const int tid = threadIdx.x, wave = tid >> 6, lane = tid & 63;
    const int q = lane >> 4, m16 = lane & 15;
    const int wm = wave >> 2, wn = wave & 3;
    const int grp = n0 >> 10;                     // 0=k, 1=v, 2=r (uniform per block)
    #pragma unroll
    for (int a = 0; a < 2; ++a)
    #pragma unroll
    for (int mf = 0; mf < 4; ++mf)
    #pragma unroll
    for (int rg = 0; rg < 4; ++rg) {
        const int row = m0 + wm * 128 + a * 64 + mf * 16 + q * 4 + rg;
        const int t = row & (T - 1);
        const size_t rowp = (size_t)(t ? row - 1 : row) * C;   // time-mix x_prev row
        #pragma unroll
        for (int s = 0; s < 2; ++s)
        #pragma unroll
        for (int nf = 0; nf < 2; ++nf) {
            const int cc = (n0 + wn * 64 + s * 32 + nf * 16 + m16) & (C - 1);
            const float val = acc[a][s][mf][nf][rg];
            const float xp = x[rowp + cc];
            if (grp == 0) {
                const float f = tmk[cc];
                kvbuf[(size_t)row * 2048 + 2 * cc] = f2bf(val * f + xp * (1.0f - f));
            } else if (grp == 1) {
                const float f = tmv[cc];
                kvbuf[(size_t)row * 2048 + 2 * cc + 1] = f2bf(val * f + xp * (1.0f - f));
            } else {
                const float f = tmr[cc];
                rbuf[(size_t)row * C + cc] = f2bf(sigmoidf_(val * f + xp * (1.0f - f)));
            }
        }
    }
}

// ================= WKV chunked parallel scan =================
__global__ __launch_bounds__(256) void wkv_k1(
    const u32* __restrict__ kvp, const float* __restrict__ wdec, float* __restrict__ bc)
{
    const int tid = blockIdx.x * 256 + threadIdx.x;
    const int c = tid & (C - 1), ci = tid >> 10;
    const float w = wdec[c];
    const size_t L = ((size_t)(ci >> 6) * T + (size_t)(ci & (NCH - 1)) * LCH) * C + c;
    float bb = -1e38f;
    #pragma unroll 4
    for (int t = 0; t < LCH; ++t) {
        const float k = bf2f((u16)(kvp[L + (size_t)t * C] & 0xffffu));
        const float ww = w + bb;
        const float p = fmaxf(ww, k);
        const float e1 = __expf(ww - p), e2 = __expf(k - p);
        bb = p + __logf(e1 + e2 + 1e-8f);
    }
    bc[tid] = bb;
}

__global__ __launch_bounds__(256) void wkv_p1(
    const float* __restrict__ bc, const float* __restrict__ wdec, float* __restrict__ bbin)
{
    const int gid = blockIdx.x * 256 + threadIdx.x;   // 0..8191 = b*C + c
    const int c = gid & (C - 1), b = gid >> 10;
    const float Lw = (float)LCH * wdec[c];
    float bb = -1e38f;
    #pragma unroll 8
    for (int j = 0; j < NCH; ++j) {
        const int idx = (b * NCH + j) * C + c;
        bbin[idx] = bb;
        const float a = Lw + bb;
        const float bcv = bc[idx];
        const float m = fmaxf(a, bcv);
        bb = m + __logf(__expf(a - m) + __expf(bcv - m));
    }
}

__global__ __launch_bounds__(256) void wkv_k2a(
    const u32* __restrict__ kvp, const float* __restrict__ wdec,
    const float* __restrict__ bbin, float* __restrict__ logS, float* __restrict__ Rr)
{
    const int tid = blockIdx.x * 256 + threadIdx.x;
    const int c = tid & (C - 1), ci = tid >> 10;
    const float w = wdec[c];
    const size_t L = ((size_t)(ci >> 6) * T + (size_t)(ci & (NCH - 1)) * LCH) * C + c;
    float bb = bbin[tid], ls = 0.0f, R = 0.0f;
    #pragma unroll 4
    for (int t = 0; t < LCH; ++t) {
        const u32 kv = kvp[L + (size_t)t * C];
        const float k = bf2f((u16)(kv & 0xffffu)), v = bf2f((u16)(kv >> 16));
        const float ww = w + bb;
        const float p = fmaxf(ww, k);
        const float e1 = __expf(ww - p), e2 = __expf(k - p);
        R = e1 * R + e2 * v;
        ls += ww - p;                       // log of alpha product (<=0)
        bb = p + __logf(e1 + e2 + 1e-8f);
    }
    logS[tid] = ls;
    Rr[tid] = R;
}

__global__ __launch_bounds__(256) void wkv_p2(
    const float* __restrict__ logS, const float* __restrict__ Rr, float* __restrict__ aain)
{
    const int gid = blockIdx.x * 256 + threadIdx.x;   // b*C + c
    const int c = gid & (C - 1), b = gid >> 10;
    float a = 0.0f;
    #pragma unroll 8
    for (int j = 0; j < NCH; ++j) {
        const int idx = (b * NCH + j) * C + c;
        aain[idx] = a;
        a = __expf(logS[idx]) * a + Rr[idx];
    }
}

__global__ __launch_bounds__(256) void wkv_k2c(
    const u32* __restrict__ kvp, const u16* __restrict__ rbuf, const float* __restrict__ x,
    const float* __restrict__ wdec, const float* __restrict__ ufirst,
    const float* __restrict__ bbin, const float* __restrict__ aain,
    float* __restrict__ x2, float* __restrict__ state)
{
    const int tid = blockIdx.x * 256 + threadIdx.x;
    const int c = tid & (C - 1), ci = tid >> 10;
    const int b = ci >> 6, j = ci & (NCH - 1);
    const float w = wdec[c], u = ufirst[c];
    float aa = aain[tid], bb = bbin[tid];
    const size_t L = ((size_t)b * T + (size_t)j * LCH) * C + c;
    #pragma unroll 4
    for (int t = 0; t < LCH; ++t) {
        const size_t idx = L + (size_t)t * C;
        const u32 kv = kvp[idx];
        const float k = bf2f((u16)(kv & 0xffffu)), v = bf2f((u16)(kv >> 16));
        const float r = bf2f(rbuf[idx]), xv = x[idx];
        float ww = u + k;
        float p  = fmaxf(bb, ww);
        float e1 = __expf(bb - p), e2 = __expf(ww - p);
        const float y = (e1 * aa + e2 * v) / (e1 + e2 + 1e-8f);
        x2[idx] = xv + r * y;
        ww = w + bb;
        p  = fmaxf(ww, k);
        e1 = __expf(ww - p); e2 = __expf(k - p);
        aa = e1 * aa + e2 * v;
        bb = p + __logf(e1 + e2 + 1e-8f);
    }
    if (j == NCH - 1) {
        state[2 * (b * C + c)]     = aa;
        state[2 * (b * C + c) + 1] = bb;
    }
}

// ---------------- LN2 + rr + xp_s snapshot ----------------
__global__ __launch_bounds__(256) void ln2_kernel(
    const float* __restrict__ x2, const float* __restrict__ g, const float* __restrict__ b,
    const float* __restrict__ cmr, u16* __restrict__ xn, u16* __restrict__ rr,
    u16* __restrict__ xps)
{
    const int row = blockIdx.x, tid = threadIdx.x;
    const size_t base = (size_t)row * C;
    const int t = row & (T - 1);
    const size_t basep = (size_t)(row - t + (t ? t - 1 : T - 1)) * C;   // cm xp row (wraps)
    const int c = tid * 4;
    float4 v = *(const float4*)&x2[base + c];
    float s  = v.x + v.y + v.z + v.w;
    float s2 = v.x*v.x + v.y*v.y + v.z*v.z + v.w*v.w;
    #pragma unroll
    for (int off = 32; off >= 1; off >>= 1) { s += __shfl_xor(s, off); s2 += __shfl_xor(s2, off); }
    __shared__ float red[8];
    const int wave = tid >> 6, lane = tid & 63;
    if (lane == 0) { red[wave] = s; red[4 + wave] = s2; }
    __syncthreads();
    const float sum  = red[0] + red[1] + red[2] + red[3];
    const float sums = red[4] + red[5] + red[6] + red[7];
    const float mean = sum * (1.0f / C);
    const float var  = sums * (1.0f / C) - mean * mean;
    const float rstd = rsqrtf(var + 1e-5f);
    float4 gv = *(const float4*)&g[c];
    float4 bv = *(const float4*)&b[c];
    float4 fv = *(const float4*)&cmr[c];
    float4 xp = *(const float4*)&x2[basep + c];
    float xn0 = (v.x - mean) * rstd * gv.x + bv.x;
    float xn1 = (v.y - mean) * rstd * gv.y + bv.y;
    float xn2 = (v.z - mean) * rstd * gv.z + bv.z;
    float xn3 = (v.w - mean) * rstd * gv.w + bv.w;
    u16x4 o; o.x = f2bf(xn0); o.y = f2bf(xn1); o.z = f2bf(xn2); o.w = f2bf(xn3);
    *(u16x4*)&xn[base + c] = o;
    u16x4 p4; p4.x = f2bf(xp.x); p4.y = f2bf(xp.y); p4.z = f2bf(xp.z); p4.w = f2bf(xp.w);
    *(u16x4*)&xps[base + c] = p4;
    u16x4 r4;
    r4.x = f2bf(sigmoidf_(xn0 * fv.x + xp.x * (1.0f - fv.x)));
    r4.y = f2bf(sigmoidf_(xn1 * fv.y + xp.y * (1.0f - fv.y)));
    r4.z = f2bf(sigmoidf_(xn2 * fv.z + xp.z * (1.0f - fv.z)));
    r4.w = f2bf(sigmoidf_(xn3 * fv.w + xp.w * (1.0f - fv.w)));
    *(u16x4*)&rr[base + c] = r4;
}

// ---------------- GEMM2 (one 2048-col half) + cm-mix + relu^2 -> h_half (bf16) ----------------
__global__ __launch_bounds__(512, 2) void gemm2_kernel(
    const u16* __restrict__ xn, const u16* __restrict__ wt,   // wt pre-offset to half
    const u16* __restrict__ xps, const float* __restrict__ cmk,
    u16* __restrict__ hbuf, const int nbase)
{
    __shared__ __align__(16) u16 lds[8 * 8192];
    f32x4 acc[2][2][4][2];
    const int nbn = 8;
    int id = blockIdx.x;
    id = (id & 7) * (512 >> 3) + (id >> 3);
    const int m0 = (id / nbn) << 8, n0 = (id % nbn) << 8;
    gemm256_mainloop(xn, C, wt, C, 16, m0, n0, lds, acc);

    const int tid = threadIdx.x, wave = tid >> 6, lane = tid & 63;
    const int q = lane >> 4, m16 = lane & 15;
    const int wm = wave >> 2, wn = wave & 3;
    #pragma unroll
    for (int a = 0; a < 2; ++a)
    #pragma unroll
    for (int mf = 0; mf < 4; ++mf)
    #pragma unroll
    for (int rg = 0; rg < 4; ++rg) {
        const int row = m0 + wm * 128 + a * 64 + mf * 16 + q * 4 + rg;
        #pragma unroll
        for (int s = 0; s < 2; ++s)
        #pragma unroll
        for (int nf = 0; nf < 2; ++nf) {
            const int nloc = n0 + wn * 64 + s * 32 + nf * 16 + m16;  // 0..2047
            const int cc = (nbase + nloc) & (C - 1);
            const float f = cmk[cc];
            const float xp = bf2f(xps[(size_t)row * C + cc]);
            const float kk = acc[a][s][mf][nf][rg] * f + xp * (1.0f - f);
            const float h = fmaxf(kk, 0.0f);
            hbuf[(size_t)row * 2048 + nloc] = f2bf(h * h);
        }
    }
}

// ---------------- GEMM3 (K=2048 half) + residual epilogue, accumulates into out ----------------
__global__ __launch_bounds__(512, 2) void gemm3_kernel(
    const u16* __restrict__ hbuf, const u16* __restrict__ wt,  // wt pre-offset to half
    const u16* __restrict__ rr, float* __restrict__ out)
{
    __shared__ __align__(16) u16 lds[8 * 8192];
    f32x4 acc[2][2][4][2];
    const int nbn = 4;
    int id = blockIdx.x;
    id = (id & 7) * (256 >> 3) + (id >> 3);
    const int m0 = (id / nbn) << 8, n0 = (id % nbn) << 8;
    gemm256_mainloop(hbuf, 2048, wt, 4096, 32, m0, n0, lds, acc);

    const int tid = threadIdx.x, wave = tid >> 6, lane = tid & 63;
    const int q = lane >> 4, m16 = lane & 15;
    const int wm = wave >> 2, wn = wave & 3;
    #pragma unroll
    for (int a = 0; a < 2; ++a)
    #pragma unroll
    for (int mf = 0; mf < 4; ++mf)
    #pragma unroll
    for (int rg = 0; rg < 4; ++rg) {
        const int row = m0 + wm * 128 + a * 64 + mf * 16 + q * 4 + rg;
        #pragma unroll
        for (int s = 0; s < 2; ++s)
        #pragma unroll
        for (int nf = 0; nf < 2; ++nf) {
            const int cc = n0 + wn * 64 + s * 32 + nf * 16 + m16;
            const size_t idx = (size_t)row * C + cc;
            const float base = out[idx];   // pass0: x2; pass1: partial result
            out[idx] = base + bf2f(rr[idx]) * acc[a][s][mf][nf][rg];
        }
    }
}

// ---------------- workspace layout (byte offsets), total 176 MB ----------------
#define OFF_WT_CM  0            //  8 MB  (4096 x 1024 bf16)
#define OFF_WT_CP  8388608      //  8 MB  (1024 x 4096 bf16)
#define OFF_XN     16777216     // 32 MB  (M x C bf16; LN1 then LN2)
#define OFF_KV     50331648     // 64 MB  (M x C packed (k,v) bf16 pairs)
#define OFF_H      OFF_KV       // 64 MB  (M x 2048 bf16 half; overlays kv, dead after wkv)
#define OFF_RB     117440512    // 32 MB  (bf16; reused as rr after wkv)
#define OFF_WT_TM  150994944    //  6 MB  (3072 x 1024 bf16; dead after gemm1)
// wkv scratch overlays the wt_tm/xps extent during the scan (dead then):
#define OFF_BC     150994944    // 2 MB
#define OFF_BBIN   153092096    // 2 MB
#define OFF_LOGS   155189248    // 2 MB
#define OFF_RCH    157286400    // 2 MB
#define OFF_AAIN   159383552    // 2 MB
#define OFF_XPS    150994944    // 32 MB (bf16 shifted x2; born at ln2, after wkv)

extern "C" void kernel_launch(void* const* d_in, const int* in_sizes, int n_in,
                              void* d_out, int out_size, void* d_ws, size_t ws_size,
                              hipStream_t stream) {
    const float* x          = (const float*)d_in[0];
    const float* time_decay = (const float*)d_in[1];
    const float* time_first = (const float*)d_in[2];
    const float* W_tm       = (const float*)d_in[3];
    const float* g1         = (const float*)d_in[4];
    const float* b1         = (const float*)d_in[5];
    const float* tmk        = (const float*)d_in[6];
    const float* tmv        = (const float*)d_in[7];
    const float* tmr        = (const float*)d_in[8];
    const float* W_cm       = (const float*)d_in[9];
    const float* W_cp       = (const float*)d_in[10];
    const float* g2         = (const float*)d_in[11];
    const float* b2         = (const float*)d_in[12];
    const float* cmk        = (const float*)d_in[13];
    const float* cmr        = (const float*)d_in[14];
    float* out = (float*)d_out;

    char* ws = (char*)d_ws;
    u16*   wt_cm = (u16*)(ws + OFF_WT_CM);
    u16*   wt_cp = (u16*)(ws + OFF_WT_CP);
    u16*   xn    = (u16*)(ws + OFF_XN);
    u16*   kvbuf = (u16*)(ws + OFF_KV);
    u16*   hbuf  = (u16*)(ws + OFF_H);
    u16*   rbuf  = (u16*)(ws + OFF_RB);   // rr reuses this after wkv
    u16*   wt_tm = (u16*)(ws + OFF_WT_TM);
    u16*   xps   = (u16*)(ws + OFF_XPS);
    float* bc    = (float*)(ws + OFF_BC);
    float* bbin  = (float*)(ws + OFF_BBIN);
    float* logS  = (float*)(ws + OFF_LOGS);
    float* Rch   = (float*)(ws + OFF_RCH);
    float* aain  = (float*)(ws + OFF_AAIN);
    float* x2    = out;                    // residual stream lives in d_out

    // 1. weights -> bf16 B^T
    transpose_cast_kernel<<<dim3(1024/32, 3072/32), dim3(32, 8), 0, stream>>>(W_tm, wt_tm, 1024, 3072);
    transpose_cast_kernel<<<dim3(1024/32, 4096/32), dim3(32, 8), 0, stream>>>(W_cm, wt_cm, 1024, 4096);
    transpose_cast_kernel<<<dim3(4096/32, 1024/32), dim3(32, 8), 0, stream>>>(W_cp, wt_cp, 4096, 1024);
    // 2. LN1
    ln1_kernel<<<M, 256, 0, stream>>>(x, g1, b1, xn);
    // 3. GEMM1 + time-mix (256^2 8-phase; 768 blocks)
    gemm1_kernel<<<768, 512, 0, stream>>>(xn, wt_tm, x, tmk, tmv, tmr, kvbuf, rbuf);
    // 4. WKV chunked parallel scan (x2 -> d_out body, state -> d_out tail)
    {
        const u32* kvp = (const u32*)kvbuf;
        wkv_k1 <<<WKV_THREADS/256, 256, 0, stream>>>(kvp, time_decay, bc);
        wkv_p1 <<<(Bb*C)/256, 256, 0, stream>>>(bc, time_decay, bbin);
        wkv_k2a<<<WKV_THREADS/256, 256, 0, stream>>>(kvp, time_decay, bbin, logS, Rch);
        wkv_p2 <<<(Bb*C)/256, 256, 0, stream>>>(logS, Rch, aain);
        wkv_k2c<<<WKV_THREADS/256, 256, 0, stream>>>(kvp, rbuf, x, time_decay, time_first,
                                                     bbin, aain, x2, out + (size_t)M * C);
    }
    // 5. LN2 + rr + xp snapshot
    ln2_kernel<<<M, 256, 0, stream>>>(x2, g2, b2, cmr, xn, rbuf, xps);
    // 6+7. channel-mix GEMMs in two hidden-halves (h_half overlays dead kv)
    for (int half = 0; half < 2; ++half) {
        const int nbase = half * 2048;
        gemm2_kernel<<<512, 512, 0, stream>>>(
            xn, wt_cm + (size_t)nbase * C, xps, cmk, hbuf, nbase);
        gemm3_kernel<<<256, 512, 0, stream>>>(
            hbuf, wt_cp + nbase, rbuf, out);
    }
}